// Round 16
// baseline (40.251 us; speedup 1.0000x reference)
//
#include <hip/hip_runtime.h>
#include <math.h>

namespace {
constexpr int L = 512, S = 512, H = 8, D = 64, K64 = 64;
constexpr float LOG2E = 1.4426950408889634f;

typedef __bf16 bf16x8 __attribute__((ext_vector_type(8)));
typedef float  f32x4  __attribute__((ext_vector_type(4)));

__device__ inline f32x4 mfma16(bf16x8 a, bf16x8 b, f32x4 c) {
    return __builtin_amdgcn_mfma_f32_16x16x32_bf16(a, b, c, 0, 0, 0);
}
__device__ inline bf16x8 tobf8(f32x4 a, f32x4 b) {
    bf16x8 r;
    r[0] = (__bf16)a[0]; r[1] = (__bf16)a[1];
    r[2] = (__bf16)a[2]; r[3] = (__bf16)a[3];
    r[4] = (__bf16)b[0]; r[5] = (__bf16)b[1];
    r[6] = (__bf16)b[2]; r[7] = (__bf16)b[3];
    return r;
}

// Single kernel, single dispatch. grid 512 = XCD-swizzled (nh in {xcd,xcd+8})
// x mt(8) x dt(4); 256 threads = 4 waves.
//
// Per block:
//  1) B-build: local K/V slice (512 s x 16 d) -> bf16 feature planes in LDS
//     {(K+kl)*V, (K+kl)}; SV column-sums via LDS reduce. ONE barrier pair.
//  2) Main loop over ks (16 steps of 32 s), per wave, barrier-free:
//     - w-GEMM: two 16x16 w-tiles = mfma(u_frag, v_frag) over K=64
//       (u,v loaded f32 -> bf16 fragments in-register)
//     - + mask (f32), cast bf16, per-wave LDS scratch transpose
//       (C/D layout -> A-operand layout, double-buffered)
//     - accn += mfma(a, planeN), accd += mfma(a, planeD)
//  3) Epilogue: out = sigmoid(q) * (SV + accn) / (512 + accd)
__global__ __launch_bounds__(256) void aft_once(
    const float* __restrict__ u, const float* __restrict__ v,
    const float* __restrict__ mask, const float* __restrict__ keys,
    const float* __restrict__ values, const float* __restrict__ klen,
    const float* __restrict__ queries, float* __restrict__ out)
{
    __shared__ __bf16 planeN[16 * 520];        // 16.25 KB  feature (K+kl)*V
    __shared__ __bf16 planeD[16 * 520];        // 16.25 KB  feature (K+kl)
    __shared__ __bf16 wscr[4][2][16 * 40];     // 10 KB     per-wave dbl scratch
    __shared__ float  svred[64 * 17];          // 4.25 KB
    __shared__ float  svl[16];

    const int b = blockIdx.x;
    const int xcd = b & 7;
    const int i = b >> 3;                   // 0..63
    const int nh = xcd + ((i >> 5) << 3);   // {xcd, xcd+8}
    const int rem = i & 31;
    const int mt = rem >> 2;                // 0..7  (64 l-rows)
    const int dt = rem & 3;                 // 0..3  (16 d-cols)
    const int n = nh >> 3, h = nh & 7;

    const int t = threadIdx.x;
    const int wv = t >> 6;
    const int lane = t & 63;
    const int r = lane & 15;
    const int kg = lane >> 4;

    // ---- phase 1: B-panel build (local K/V slice) ----
    const int d4 = (t & 3) << 2;            // d offset 0,4,8,12
    const int sb0 = t >> 2;                 // 0..63
    float sva[4] = {0.f, 0.f, 0.f, 0.f};
    const size_t kvbase = ((size_t)n * S * H + h) * D + dt * 16 + d4;
    #pragma unroll
    for (int r8 = 0; r8 < 8; ++r8) {
        const int s = sb0 + (r8 << 6);
        const float kl = klen[n * S + s];
        const f32x4 K4 = *(const f32x4*)(keys + kvbase + (size_t)s * (H * D));
        const f32x4 V4 = *(const f32x4*)(values + kvbase + (size_t)s * (H * D));
        #pragma unroll
        for (int j = 0; j < 4; ++j) {
            const float kj = K4[j] + kl;
            planeN[(d4 + j) * 520 + s] = (__bf16)(kj * V4[j]);
            planeD[(d4 + j) * 520 + s] = (__bf16)kj;
            sva[j] += V4[j];
        }
    }
    #pragma unroll
    for (int j = 0; j < 4; ++j) svred[sb0 * 17 + d4 + j] = sva[j];

    // early epilogue loads (input-only; hide under build)
    const int dcol = dt * 16 + r;
    const int l0w = mt * 64 + wv * 16;
    float qv[4];
    size_t qidx[4];
    #pragma unroll
    for (int rr = 0; rr < 4; ++rr) {
        const int l = l0w + kg * 4 + rr;
        qidx[rr] = (((size_t)n * L + l) * H + h) * D + dcol;
        qv[rr] = queries[qidx[rr]];
    }

    // u fragments (A-operand of w-GEMM): lane r = l-row, kg = k-octet
    const float* urow = u + (size_t)(l0w + r) * K64 + kg * 8;
    const bf16x8 u0 = tobf8(*(const f32x4*)urow, *(const f32x4*)(urow + 4));
    const bf16x8 u1 = tobf8(*(const f32x4*)(urow + 32), *(const f32x4*)(urow + 36));

    __syncthreads();
    if (t < 16) {
        float ssum = 0.f;
        #pragma unroll
        for (int j = 0; j < 64; ++j) ssum += svred[j * 17 + t];
        svl[t] = ssum;
    }
    __syncthreads();

    // mask base for C/D rows (row = kg*4 + reg, col = st*16 + r)
    const float* mbase = mask + (size_t)(l0w + kg * 4) * S + r;

    f32x4 accn = {0.f, 0.f, 0.f, 0.f};
    f32x4 accd = {0.f, 0.f, 0.f, 0.f};

    __bf16* const scrA = &wscr[wv][0][0];
    __bf16* const scrB = &wscr[wv][1][0];

    #pragma unroll 2
    for (int ks = 0; ks < 16; ++ks) {
        __bf16* const scr = (ks & 1) ? scrB : scrA;
        // two w-tiles (s-tiles 2ks, 2ks+1), K = 64
        #pragma unroll
        for (int half = 0; half < 2; ++half) {
            const int st = ks * 2 + half;
            const float* vrow = v + (size_t)(st * 16 + r) * K64 + kg * 8;
            const bf16x8 vf0 = tobf8(*(const f32x4*)vrow,
                                     *(const f32x4*)(vrow + 4));
            const bf16x8 vf1 = tobf8(*(const f32x4*)(vrow + 32),
                                     *(const f32x4*)(vrow + 36));
            f32x4 wacc = {0.f, 0.f, 0.f, 0.f};
            wacc = mfma16(u0, vf0, wacc);
            wacc = mfma16(u1, vf1, wacc);
            const int colb = half * 16 + r;
            #pragma unroll
            for (int reg = 0; reg < 4; ++reg) {
                const float wt = wacc[reg] + mbase[(size_t)reg * S + st * 16];
                scr[(kg * 4 + reg) * 40 + colb] = (__bf16)wt;
            }
        }
        // A-fragment: lane r = l-row, kg = k-octet along s (wave-local LDS,
        // compiler inserts the lgkmcnt wait for the write->read dependency)
        const bf16x8 a  = *(const bf16x8*)(scr + r * 40 + kg * 8);
        const bf16x8 bn = *(const bf16x8*)(planeN + r * 520 + ks * 32 + kg * 8);
        const bf16x8 bd = *(const bf16x8*)(planeD + r * 520 + ks * 32 + kg * 8);
        accn = mfma16(a, bn, accn);
        accd = mfma16(a, bd, accd);
        if ((ks & 3) == 3) __syncthreads();   // keep waves in-phase for L1 reuse
    }

    const float sv = svl[r];
    #pragma unroll
    for (int rr = 0; rr < 4; ++rr) {
        const float sig =
            __builtin_amdgcn_rcpf(1.0f + __builtin_amdgcn_exp2f(-qv[rr] * LOG2E));
        const float numv = sv + accn[rr];
        const float denv = 512.0f + accd[rr];
        out[qidx[rr]] = sig * numv * __builtin_amdgcn_rcpf(denv);
    }
}
} // namespace

extern "C" void kernel_launch(void* const* d_in, const int* in_sizes, int n_in,
                              void* d_out, int out_size, void* d_ws, size_t ws_size,
                              hipStream_t stream)
{
    const float* queries = (const float*)d_in[0];
    const float* keys    = (const float*)d_in[1];
    const float* values  = (const float*)d_in[2];
    const float* mask    = (const float*)d_in[3];
    const float* klen    = (const float*)d_in[4];
    const float* u       = (const float*)d_in[5];
    const float* v       = (const float*)d_in[6];
    float* out = (float*)d_out;

    aft_once<<<dim3(512), dim3(256), 0, stream>>>(
        u, v, mask, keys, values, klen, queries, out);
}

// Round 18
// 15.732 us; speedup vs baseline: 2.5586x; 2.5586x over previous
//
#include <hip/hip_runtime.h>
#include <math.h>

namespace {
constexpr int L = 512, S = 512, H = 8, D = 64, K64 = 64;
constexpr float LOG2E = 1.4426950408889634f;
constexpr int SCW = 40;              // w-scratch stride (elems): 80 B -> 16B-aligned b128 reads

typedef __bf16 bf16x8 __attribute__((ext_vector_type(8)));
typedef __bf16 bf16x4 __attribute__((ext_vector_type(4)));
typedef float  f32x4  __attribute__((ext_vector_type(4)));

__device__ inline f32x4 mfma16(bf16x8 a, bf16x8 b, f32x4 c) {
    return __builtin_amdgcn_mfma_f32_16x16x32_bf16(a, b, c, 0, 0, 0);
}
__device__ inline bf16x8 tobf8(f32x4 a, f32x4 b) {
    bf16x8 r;
    r[0] = (__bf16)a[0]; r[1] = (__bf16)a[1];
    r[2] = (__bf16)a[2]; r[3] = (__bf16)a[3];
    r[4] = (__bf16)b[0]; r[5] = (__bf16)b[1];
    r[6] = (__bf16)b[2]; r[7] = (__bf16)b[3];
    return r;
}

// Single dispatch. grid 256 = XCD-swizzled nh(16) x mt(8) x dt(2); 512 thr = 8 waves.
// Wave wv: lw = wv&3 -> 16 l-rows (l0w = mt*64+lw*16); dh = wv>>2 -> 16 d-cols.
// LDS:
//   vf  [32 st][2 kh][64 lane] bf16x8 = 64 KB   v fragments (w-GEMM B-operand)
//   lB  [2 pl][2 cg][16 ks][64 lane] bf16x8 = 64 KB  feature planes {(K+kl)*V, K+kl}
//   wscr[8 wv][2][16*SCW] bf16 = 20 KB          per-wave double scratch (w tiles)
// Main loop (per wave, barrier-free): w = mfma(u,vf) +mask -> scratch -> a-frag
//   -> accn += mfma(a, lB_N), accd += mfma(a, lB_D).
__global__ __launch_bounds__(512, 1) void aft_once(
    const float* __restrict__ u, const float* __restrict__ v,
    const float* __restrict__ mask, const float* __restrict__ keys,
    const float* __restrict__ values, const float* __restrict__ klen,
    const float* __restrict__ queries, float* __restrict__ out)
{
    __shared__ bf16x8 vf[4096];           // 64 KB
    __shared__ bf16x8 lB[4096];           // 64 KB
    __shared__ __bf16 wscr[8][2][16 * SCW];  // 20 KB
    __shared__ float  svred[32][17];      // 2.2 KB
    __shared__ float  svl[32];

    const int b = blockIdx.x;
    const int xcd = b & 7;
    const int i = b >> 3;                  // 0..31
    const int nh = xcd + ((i >> 4) << 3);  // {xcd, xcd+8}
    const int rem = i & 15;
    const int mt = rem >> 1;               // 0..7 (64 l-rows)
    const int dt = rem & 1;                // 0..1 (32 d-cols)
    const int n = nh >> 3, h = nh & 7;

    const int t = threadIdx.x;
    const int wv = t >> 6;
    const int lane = t & 63;
    const int r = lane & 15;
    const int kg = lane >> 4;
    const int lw = wv & 3;
    const int dh = wv >> 2;
    const int l0w = mt * 64 + lw * 16;

    // ---- stage v -> LDS fragments (coalesced rows; unit = st*128+kh*64+kg*16+r) ----
    {
        const int rq = t >> 4;             // 0..31
        const int c4 = (t & 15) << 2;      // 0..60
        const int kh = c4 >> 5, kgv = (c4 >> 3) & 3, e0 = c4 & 7;
        __bf16* vfE = (__bf16*)vf;
        #pragma unroll
        for (int rd = 0; rd < 16; ++rd) {
            const int row = rq + rd * 32;
            const f32x4 v4 = *(const f32x4*)(v + (size_t)row * K64 + c4);
            bf16x4 p;
            p[0] = (__bf16)v4[0]; p[1] = (__bf16)v4[1];
            p[2] = (__bf16)v4[2]; p[3] = (__bf16)v4[3];
            const int unit = ((row >> 4) * 128) + (kh * 64) + (kgv * 16) + (row & 15);
            *(bf16x4*)(vfE + unit * 8 + e0) = p;
        }
    }

    // ---- stage K/V feature planes in fragment layout + SV partials ----
    // FIX vs R17: full s-coverage — 4 blk x 8 j = 32 s per thread (sgg in [0,64)).
    {
        const int dl = t & 31;             // local d
        const int sg0 = t >> 5;            // 0..15
        const int cg = dl >> 4, rb = dl & 15;
        float sum = 0.f;
        #pragma unroll
        for (int blk = 0; blk < 4; ++blk) {
            const int sgg = sg0 + (blk << 4);   // 0..63 (8-s groups)
            const int ksb = sgg >> 2, kgb = sgg & 3;
            bf16x8 nv, dv;
            #pragma unroll
            for (int j = 0; j < 8; ++j) {
                const int s = sgg * 8 + j;
                const float kl = klen[n * S + s];
                const size_t gi = (((size_t)n * S + s) * H + h) * D + dt * 32 + dl;
                const float kk = keys[gi] + kl;
                const float vv = values[gi];
                nv[j] = (__bf16)(kk * vv);
                dv[j] = (__bf16)kk;
                sum += vv;
            }
            lB[((0 * 2 + cg) * 16 + ksb) * 64 + kgb * 16 + rb] = nv;
            lB[((1 * 2 + cg) * 16 + ksb) * 64 + kgb * 16 + rb] = dv;
        }
        svred[dl][sg0] = sum;
    }

    // ---- early epilogue loads (input-only) ----
    const int dcol = dt * 32 + dh * 16 + r;
    float qv[4];
    size_t qidx[4];
    #pragma unroll
    for (int rr = 0; rr < 4; ++rr) {
        const int l = l0w + kg * 4 + rr;
        qidx[rr] = (((size_t)n * L + l) * H + h) * D + dcol;
        qv[rr] = queries[qidx[rr]];
    }

    // ---- u fragments (w-GEMM A-operand): lane r = l-row, kg = k-octet ----
    const float* urow = u + (size_t)(l0w + r) * K64 + kg * 8;
    const bf16x8 u0 = tobf8(*(const f32x4*)urow, *(const f32x4*)(urow + 4));
    const bf16x8 u1 = tobf8(*(const f32x4*)(urow + 32), *(const f32x4*)(urow + 36));

    __syncthreads();
    if (t < 32) {
        float ssum = 0.f;
        #pragma unroll
        for (int j = 0; j < 16; ++j) ssum += svred[t][j];
        svl[t] = ssum;
    }
    __syncthreads();

    const float* mbase = mask + (size_t)(l0w + kg * 4) * S + r;

    f32x4 accn = {0.f, 0.f, 0.f, 0.f};
    f32x4 accd = {0.f, 0.f, 0.f, 0.f};
    __bf16* const scr0 = &wscr[wv][0][0];
    __bf16* const scr1 = &wscr[wv][1][0];

    #pragma unroll 2
    for (int ks = 0; ks < 16; ++ks) {
        __bf16* const scr = (ks & 1) ? scr1 : scr0;
        #pragma unroll
        for (int half = 0; half < 2; ++half) {
            const int st = ks * 2 + half;
            const bf16x8 vf0 = vf[st * 128 + lane];
            const bf16x8 vf1 = vf[st * 128 + 64 + lane];
            f32x4 wacc = {0.f, 0.f, 0.f, 0.f};
            wacc = mfma16(u0, vf0, wacc);
            wacc = mfma16(u1, vf1, wacc);
            const int colb = half * 16 + r;
            #pragma unroll
            for (int reg = 0; reg < 4; ++reg) {
                const float wt = wacc[reg] + mbase[(size_t)reg * S + st * 16];
                scr[(kg * 4 + reg) * SCW + colb] = (__bf16)wt;
            }
        }
        const bf16x8 a  = *(const bf16x8*)(scr + r * SCW + kg * 8);
        const bf16x8 bn = lB[((0 * 2 + dh) * 16 + ks) * 64 + lane];
        const bf16x8 bd = lB[((1 * 2 + dh) * 16 + ks) * 64 + lane];
        accn = mfma16(a, bn, accn);
        accd = mfma16(a, bd, accd);
    }

    const float sv = svl[dh * 16 + r];
    #pragma unroll
    for (int rr = 0; rr < 4; ++rr) {
        const float sig =
            __builtin_amdgcn_rcpf(1.0f + __builtin_amdgcn_exp2f(-qv[rr] * LOG2E));
        const float numv = sv + accn[rr];
        const float denv = 512.0f + accd[rr];
        out[qidx[rr]] = sig * numv * __builtin_amdgcn_rcpf(denv);
    }
}
} // namespace

extern "C" void kernel_launch(void* const* d_in, const int* in_sizes, int n_in,
                              void* d_out, int out_size, void* d_ws, size_t ws_size,
                              hipStream_t stream)
{
    const float* queries = (const float*)d_in[0];
    const float* keys    = (const float*)d_in[1];
    const float* values  = (const float*)d_in[2];
    const float* mask    = (const float*)d_in[3];
    const float* klen    = (const float*)d_in[4];
    const float* u       = (const float*)d_in[5];
    const float* v       = (const float*)d_in[6];
    float* out = (float*)d_out;

    aft_once<<<dim3(256), dim3(512), 0, stream>>>(
        u, v, mask, keys, values, klen, queries, out);
}